// Round 12
// baseline (642.935 us; speedup 1.0000x reference)
//
#include <hip/hip_runtime.h>
#include <hip/hip_fp16.h>

// ---------------------------------------------------------------------------
// GIN (5 layers) + BN + graph pooling + MLP head.
// R27: (1) unfuse prep from fill -- R26's merge cost ~15-20us (82 vs 55+8;
//      streaming prep contends with the scatter's line traffic, milder R17).
//      (2) bnpart 32 -> 256 buckets: phase-C atomic contention 49 -> 6
//      blocks/bucket. Finalize reads 128KB but runs as a straggler INSIDE
//      the pgather dispatch (gathers ~55us) with a 4-wave striped sum
//      (~4us) -> fully hidden. (R22's idea done right: bounded read,
//      co-dispatched with long-running blocks.)
// R26 (best, 609us): padded-bucket CSR (col[d*64+rank], NO scan), pipelined
//      histw -> fill; scang folded into gather16.
// R24: BN-affine fold (gather stores raw sums; mlp applies a*s+b*(1+deg));
//      pool_bn merged into gather dispatch (k_pgather), off the chain.
// Lessons: atomics and dependent scatters must not share a kernel (R25:
//      142us); never one-block a >100KB reduction in a SHORT dispatch (R22);
//      gather = fabric floor for random 128B rows, 1 wave = 1 node; don't
//      fuse INTO gather; hist's atomic pipe tolerates no co-tenants.
// R16: per-wave 16-node C^T MFMA tiles, fp32-equiv hi/lo weight split.
// ---------------------------------------------------------------------------

#define DEGCAP 64
#define BNBKT 256

typedef _Float16 half_t;
typedef half_t f16x8 __attribute__((ext_vector_type(8)));
typedef float f32x4 __attribute__((ext_vector_type(4)));

__device__ __forceinline__ unsigned short f2h(float f) {
    return __half_as_ushort(__float2half_rn(f));
}
__device__ __forceinline__ float h2f(unsigned short s) {
    return __half2float(__ushort_as_half(s));
}
__device__ __forceinline__ f32x4 mfma16(f16x8 a, f16x8 b, f32x4 c) {
    return __builtin_amdgcn_mfma_f32_16x16x32_f16(a, b, c, 0, 0, 0);
}

// BN finalize helper: 4-wave striped sum over BNBKT buckets -> a,b coefs.
__device__ __forceinline__ void bn_finalize(const float* __restrict__ bnpart,
        const float* __restrict__ gamma, const float* __restrict__ beta,
        float* __restrict__ a_out, float* __restrict__ b_out, int N) {
    __shared__ float red[2][4][64];
    int t = threadIdx.x;
    int c = t & 63;
    int stripe = t >> 6;
    float s = 0.f, q = 0.f;
    for (int i = stripe; i < BNBKT; i += 4) {
        s += bnpart[(size_t)i * 128 + c];
        q += bnpart[(size_t)i * 128 + 64 + c];
    }
    red[0][stripe][c] = s;
    red[1][stripe][c] = q;
    __syncthreads();
    if (t < 64) {
        float ss = (red[0][0][t] + red[0][1][t]) + (red[0][2][t] + red[0][3][t]);
        float sq = (red[1][0][t] + red[1][1][t]) + (red[1][2][t] + red[1][3][t]);
        float invN = 1.0f / (float)N;
        float mu = ss * invN;
        float var = sq * invN - mu * mu;
        float ac = gamma[t] * rsqrtf(var + 1e-5f);
        a_out[t] = ac;
        b_out[t] = beta[t] - mu * ac;
    }
}

// Merged: blocks [0,10) pack W^T into MFMA A-fragments (hi/lo split);
// blocks [10,..) edge histogram + rank (atomic returns slot).
__global__ __launch_bounds__(256) void k_histw(const int* __restrict__ dst, int E,
        int* __restrict__ cnt_node, int* __restrict__ rank_,
        const float* __restrict__ W1a, const float* __restrict__ W1b,
        const float* __restrict__ Wa, const float* __restrict__ Wb,
        half_t* __restrict__ wout) {
    if ((int)blockIdx.x < 10) {
        int mat = blockIdx.x;      // 0=W1a 1=W1b 2..5=Wa[l] 6..9=Wb[l]
        const float* W; int K;
        if (mat == 0)      { W = W1a; K = 11; }
        else if (mat == 1) { W = W1b; K = 64; }
        else if (mat < 6)  { W = Wa + (mat - 2) * 4096; K = 64; }
        else               { W = Wb + (mat - 6) * 4096; K = 64; }
        int lane = threadIdx.x & 63, m = threadIdx.x >> 6;
        int row = 16 * m + (lane & 15);
#pragma unroll
        for (int ks = 0; ks < 2; ++ks) {
            f16x8 hi, lo;
#pragma unroll
            for (int j = 0; j < 8; ++j) {
                int k = 32 * ks + (lane >> 4) * 8 + j;
                float w = (k < K) ? W[k * 64 + row] : 0.f;
                half_t h = (half_t)w;
                hi[j] = h;
                lo[j] = (half_t)(w - (float)h);
            }
            size_t base = ((size_t)mat * 4 + m) * 4 + (size_t)ks * 2;
            *(f16x8*)(wout + ((base + 0) * 64 + lane) * 8) = hi;
            *(f16x8*)(wout + ((base + 1) * 64 + lane) * 8) = lo;
        }
    } else {
        int i = ((int)blockIdx.x - 10) * 256 + threadIdx.x;
        if (i < E) rank_[i] = atomicAdd(&cnt_node[dst[i]], 1);
    }
}

// CSR fill into padded buckets: pure scatter, no atomics, no rp read.
__global__ __launch_bounds__(256) void k_fill(
        const int* __restrict__ src, const int* __restrict__ dst,
        const int* __restrict__ rank_, int E, int* __restrict__ col) {
    int e = blockIdx.x * blockDim.x + threadIdx.x;
    if (e < E) {
        __builtin_nontemporal_store(src[e],
            &col[(size_t)dst[e] * DEGCAP + rank_[e]]);
    }
}

// Node prep: x -> fp16 padded 16ch, graph counts
__global__ __launch_bounds__(256) void k_prep(const float* __restrict__ x,
        unsigned short* __restrict__ x16h, const int* __restrict__ batch,
        int* __restrict__ cnt_graph, int N) {
    int i = blockIdx.x * blockDim.x + threadIdx.x;
    if (i < N) {
        atomicAdd(&cnt_graph[batch[i]], 1);
#pragma unroll
        for (int k = 0; k < 11; ++k) x16h[i * 16 + k] = f2h(x[i * 11 + k]);
#pragma unroll
        for (int k = 11; k < 16; ++k) x16h[i * 16 + k] = 0;
    }
}

// Layer-1 gather in padded 11->16 dim fp16 space: wave = 1 node, 4 edges per
// step (16 lanes per edge), 4-deep -> 16 edges in flight. fp32 out.
// Extra block (blockIdx.x == nb_node): exclusive scan cntg -> gstart.
__global__ __launch_bounds__(256, 8) void k_gather16(
        const unsigned short* __restrict__ x16h, float* __restrict__ h16,
        const int* __restrict__ cnt, const int* __restrict__ col, int N,
        int nb_node, const int* __restrict__ cntg, int Gn,
        int* __restrict__ gstart) {
    if ((int)blockIdx.x == nb_node) {
        __shared__ int sd[256];
        int t = threadIdx.x;
        int base = t * 4;
        int v0 = (base + 0 < Gn) ? cntg[base + 0] : 0;
        int v1 = (base + 1 < Gn) ? cntg[base + 1] : 0;
        int v2 = (base + 2 < Gn) ? cntg[base + 2] : 0;
        int v3 = (base + 3 < Gn) ? cntg[base + 3] : 0;
        int tsum = v0 + v1 + v2 + v3;
        sd[t] = tsum;
        __syncthreads();
        for (int off = 1; off < 256; off <<= 1) {
            int val = (t >= off) ? sd[t - off] : 0;
            __syncthreads();
            sd[t] += val;
            __syncthreads();
        }
        int excl = sd[t] - tsum;
        if (base + 0 < Gn) gstart[base + 0] = excl;
        if (base + 1 < Gn) gstart[base + 1] = excl + v0;
        if (base + 2 < Gn) gstart[base + 2] = excl + v0 + v1;
        if (base + 3 < Gn) gstart[base + 3] = excl + v0 + v1 + v2;
        if (t == 255) gstart[Gn] = sd[255];     // = N
        return;
    }
    int lane = threadIdx.x & 63, wv = threadIdx.x >> 6;
    int n = blockIdx.x * 4 + wv;
    if (n >= N) return;
    int sub = lane >> 4, c = lane & 15;
    int start = n * DEGCAP;
    int end = start + cnt[n];
    float s0 = 0.f, s1 = 0.f, s2 = 0.f, s3 = 0.f;
    int eb = start;
    for (; eb + 16 <= end; eb += 16) {
        int j0 = col[eb + sub];
        int j1 = col[eb + 4 + sub];
        int j2 = col[eb + 8 + sub];
        int j3 = col[eb + 12 + sub];
        s0 += h2f(x16h[(size_t)j0 * 16 + c]);
        s1 += h2f(x16h[(size_t)j1 * 16 + c]);
        s2 += h2f(x16h[(size_t)j2 * 16 + c]);
        s3 += h2f(x16h[(size_t)j3 * 16 + c]);
    }
    for (; eb + 4 <= end; eb += 4) {
        int j0 = col[eb + sub];
        s0 += h2f(x16h[(size_t)j0 * 16 + c]);
    }
    for (int e = eb + sub; e < end; e += 4) {
        s1 += h2f(x16h[(size_t)col[e] * 16 + c]);
    }
    float s = (s0 + s1) + (s2 + s3);
    s += __shfl_xor(s, 16);
    s += __shfl_xor(s, 32);
    if (lane < 16) {
        h16[(size_t)n * 16 + lane] = s + h2f(x16h[(size_t)n * 16 + lane]);
    }
}

// Merged pool + gather (layers 2-5). Blocks [0, nbp]: graph pooling of the
// JUST-WRITTEN vb (segment-sum, zero atomics) + BN finalize (block nbp,
// striped over BNBKT buckets, hidden under the ~55us gather blocks).
// Blocks (nbp, ...): gather for the NEXT layer -- stores RAW sums (fp16),
// BN affine deferred to k_mlp (the R24 fold that makes these independent).
__global__ __launch_bounds__(256, 8) void k_pgather(
        const unsigned short* __restrict__ vb, const int* __restrict__ gstart,
        float* __restrict__ Sg,
        const float* __restrict__ bnpart, const float* __restrict__ gamma,
        const float* __restrict__ beta, float* __restrict__ a_out,
        float* __restrict__ b_out,
        unsigned short* __restrict__ aggh, const int* __restrict__ cnt,
        const int* __restrict__ col,
        int N, int Gn, int nbp) {
    if ((int)blockIdx.x <= nbp) {
        // ---- pool role ----
        if ((int)blockIdx.x == nbp) {
            bn_finalize(bnpart, gamma, beta, a_out, b_out, N);
            return;
        }
        int lane = threadIdx.x & 63, wv = threadIdx.x >> 6;
        int g = blockIdx.x * 4 + wv;
        if (g >= Gn) return;
        int sub = lane >> 4, q = lane & 15;
        int s = gstart[g], e = gstart[g + 1];
        float4 a0 = make_float4(0, 0, 0, 0), a1 = make_float4(0, 0, 0, 0);
        float4 a2 = make_float4(0, 0, 0, 0), a3 = make_float4(0, 0, 0, 0);
        int eb = s;
        for (; eb + 16 <= e; eb += 16) {
            ushort4 u0 = *(const ushort4*)(vb + (size_t)(eb + 0 + sub) * 64 + q * 4);
            ushort4 u1 = *(const ushort4*)(vb + (size_t)(eb + 4 + sub) * 64 + q * 4);
            ushort4 u2 = *(const ushort4*)(vb + (size_t)(eb + 8 + sub) * 64 + q * 4);
            ushort4 u3 = *(const ushort4*)(vb + (size_t)(eb + 12 + sub) * 64 + q * 4);
            a0.x += h2f(u0.x); a0.y += h2f(u0.y); a0.z += h2f(u0.z); a0.w += h2f(u0.w);
            a1.x += h2f(u1.x); a1.y += h2f(u1.y); a1.z += h2f(u1.z); a1.w += h2f(u1.w);
            a2.x += h2f(u2.x); a2.y += h2f(u2.y); a2.z += h2f(u2.z); a2.w += h2f(u2.w);
            a3.x += h2f(u3.x); a3.y += h2f(u3.y); a3.z += h2f(u3.z); a3.w += h2f(u3.w);
        }
        for (; eb + 4 <= e; eb += 4) {
            ushort4 u0 = *(const ushort4*)(vb + (size_t)(eb + sub) * 64 + q * 4);
            a0.x += h2f(u0.x); a0.y += h2f(u0.y); a0.z += h2f(u0.z); a0.w += h2f(u0.w);
        }
        if (eb + sub < e) {
            ushort4 u0 = *(const ushort4*)(vb + (size_t)(eb + sub) * 64 + q * 4);
            a1.x += h2f(u0.x); a1.y += h2f(u0.y); a1.z += h2f(u0.z); a1.w += h2f(u0.w);
        }
        float4 t;
        t.x = (a0.x + a1.x) + (a2.x + a3.x);
        t.y = (a0.y + a1.y) + (a2.y + a3.y);
        t.z = (a0.z + a1.z) + (a2.z + a3.z);
        t.w = (a0.w + a1.w) + (a2.w + a3.w);
#pragma unroll
        for (int off = 16; off < 64; off <<= 1) {
            t.x += __shfl_xor(t.x, off); t.y += __shfl_xor(t.y, off);
            t.z += __shfl_xor(t.z, off); t.w += __shfl_xor(t.w, off);
        }
        if (sub == 0) {
            *(float4*)(Sg + (size_t)g * 64 + q * 4) = t;
        }
        return;
    }
    // ---- gather role: raw sums, no BN affine ----
    int bid = (int)blockIdx.x - nbp - 1;
    int lane = threadIdx.x & 63, wv = threadIdx.x >> 6;
    int n = bid * 4 + wv;
    if (n >= N) return;
    int start = n * DEGCAP;
    int end = start + cnt[n];
    float s[16];
#pragma unroll
    for (int u = 0; u < 16; ++u) s[u] = 0.f;
    s[0] = h2f(vb[(size_t)n * 64 + lane]);
    int e = start;
    for (; e + 16 <= end; e += 16) {
        int j[16];
#pragma unroll
        for (int u = 0; u < 16; ++u) j[u] = col[e + u];
#pragma unroll
        for (int u = 0; u < 16; ++u)
            s[u] += h2f(vb[(size_t)j[u] * 64 + lane]);
    }
    for (; e + 4 <= end; e += 4) {
        int j0 = col[e + 0], j1 = col[e + 1], j2 = col[e + 2], j3 = col[e + 3];
        s[0] += h2f(vb[(size_t)j0 * 64 + lane]);
        s[1] += h2f(vb[(size_t)j1 * 64 + lane]);
        s[2] += h2f(vb[(size_t)j2 * 64 + lane]);
        s[3] += h2f(vb[(size_t)j3 * 64 + lane]);
    }
    for (; e < end; ++e) s[0] += h2f(vb[(size_t)col[e] * 64 + lane]);
#pragma unroll
    for (int u = 8; u > 0; u >>= 1)
#pragma unroll
        for (int v2 = 0; v2 < u; ++v2) s[v2] += s[v2 + u];
    aggh[(size_t)n * 64 + lane] = f2h(s[0]);
}

// MLP: one block = one 64-node tile, 4 waves x 16 nodes each. Both matvecs
// via mfma_f32_16x16x32_f16 on C^T = W^T x H^T (wave-private, barrier-free).
// FIRST=false: input = RAW sums; BN affine v = a*s + b*(1+deg) applied here
// in fp32 (deg = cnt[node]), hi/lo split into the B-operand.
// Phase C: fp16 store + block-aggregated BN partials (128 atomic dwords per
// block into one of BNBKT=256 buckets -> ~6 blocks/bucket contention).
template <bool FIRST>
__global__ __launch_bounds__(256, 4) void k_mlp(
        const void* __restrict__ aggp, unsigned short* __restrict__ vout,
        const half_t* __restrict__ wf1, const float* __restrict__ ba,
        const half_t* __restrict__ wf2, const float* __restrict__ bb,
        float* __restrict__ bnpart,
        const float* __restrict__ ab_prev, const int* __restrict__ cnt,
        int N) {
    __shared__ float hb[64 * 64];
    __shared__ float4 bnS[4][16], bnQ[4][16];
    float4* hb4 = (float4*)hb;
    const int tid = threadIdx.x;
    const int lane = tid & 63;
    const int wv = tid >> 6;
    const int n0 = blockIdx.x * 64;
    const int l15 = lane & 15;
    const int g = lane >> 4;
    const int nt = wv * 16 + l15;          // tile-local node (B-operand col)
    const int node = n0 + nt;

    // ---- matvec1: C1^T[ch_out][node]; bias folded into acc init.
    f32x4 acc[4];
#pragma unroll
    for (int m = 0; m < 4; ++m) {
        float4 bv = *(const float4*)(ba + 16 * m + 4 * g);
        acc[m][0] = bv.x; acc[m][1] = bv.y; acc[m][2] = bv.z; acc[m][3] = bv.w;
    }

    if (FIRST) {
        // B = H^T from h16 (fp32 Nx16), hi/lo split (exact).
        f16x8 bhi, blo;
#pragma unroll
        for (int j = 0; j < 8; ++j) { bhi[j] = (half_t)0; blo[j] = (half_t)0; }
        if (g < 2 && node < N) {
            const float* h16 = (const float*)aggp;
            float4 v0 = *(const float4*)(h16 + (size_t)node * 16 + g * 8);
            float4 v1 = *(const float4*)(h16 + (size_t)node * 16 + g * 8 + 4);
            float v[8] = {v0.x, v0.y, v0.z, v0.w, v1.x, v1.y, v1.z, v1.w};
#pragma unroll
            for (int j = 0; j < 8; ++j) {
                half_t h = (half_t)v[j];
                bhi[j] = h;
                blo[j] = (half_t)(v[j] - (float)h);
            }
        }
#pragma unroll
        for (int m = 0; m < 4; ++m) {
            f16x8 ah = *(const f16x8*)(wf1 + (size_t)((m * 4 + 0) * 64 + lane) * 8);
            f16x8 al = *(const f16x8*)(wf1 + (size_t)((m * 4 + 1) * 64 + lane) * 8);
            acc[m] = mfma16(ah, bhi, acc[m]);
            acc[m] = mfma16(al, bhi, acc[m]);
            acc[m] = mfma16(ah, blo, acc[m]);
        }
    } else {
        // B = affine(raw sums): v = a*s + b*(1+deg), hi/lo split.
        f16x8 b0h, b0l, b1h, b1l;
#pragma unroll
        for (int j = 0; j < 8; ++j) {
            b0h[j] = (half_t)0; b0l[j] = (half_t)0;
            b1h[j] = (half_t)0; b1l[j] = (half_t)0;
        }
        if (node < N) {
            const half_t* ah16 = (const half_t*)aggp;
            f16x8 s0 = *(const f16x8*)(ah16 + (size_t)node * 64 + g * 8);
            f16x8 s1 = *(const f16x8*)(ah16 + (size_t)node * 64 + 32 + g * 8);
            float dd = (float)(1 + cnt[node]);
            float4 aA0 = *(const float4*)(ab_prev + g * 8);
            float4 aA1 = *(const float4*)(ab_prev + g * 8 + 4);
            float4 aB0 = *(const float4*)(ab_prev + 32 + g * 8);
            float4 aB1 = *(const float4*)(ab_prev + 32 + g * 8 + 4);
            float4 bA0 = *(const float4*)(ab_prev + 64 + g * 8);
            float4 bA1 = *(const float4*)(ab_prev + 64 + g * 8 + 4);
            float4 bB0 = *(const float4*)(ab_prev + 96 + g * 8);
            float4 bB1 = *(const float4*)(ab_prev + 96 + g * 8 + 4);
            float aa0[8] = {aA0.x, aA0.y, aA0.z, aA0.w, aA1.x, aA1.y, aA1.z, aA1.w};
            float aa1[8] = {aB0.x, aB0.y, aB0.z, aB0.w, aB1.x, aB1.y, aB1.z, aB1.w};
            float cc0[8] = {bA0.x, bA0.y, bA0.z, bA0.w, bA1.x, bA1.y, bA1.z, bA1.w};
            float cc1[8] = {bB0.x, bB0.y, bB0.z, bB0.w, bB1.x, bB1.y, bB1.z, bB1.w};
#pragma unroll
            for (int j = 0; j < 8; ++j) {
                float v0 = fmaf(aa0[j], (float)s0[j], cc0[j] * dd);
                half_t h0 = (half_t)v0;
                b0h[j] = h0; b0l[j] = (half_t)(v0 - (float)h0);
                float v1 = fmaf(aa1[j], (float)s1[j], cc1[j] * dd);
                half_t h1 = (half_t)v1;
                b1h[j] = h1; b1l[j] = (half_t)(v1 - (float)h1);
            }
        }
#pragma unroll
        for (int m = 0; m < 4; ++m) {
            f16x8 a0h = *(const f16x8*)(wf1 + (size_t)((m * 4 + 0) * 64 + lane) * 8);
            f16x8 a0l = *(const f16x8*)(wf1 + (size_t)((m * 4 + 1) * 64 + lane) * 8);
            f16x8 a1h = *(const f16x8*)(wf1 + (size_t)((m * 4 + 2) * 64 + lane) * 8);
            f16x8 a1l = *(const f16x8*)(wf1 + (size_t)((m * 4 + 3) * 64 + lane) * 8);
            acc[m] = mfma16(a0h, b0h, acc[m]);
            acc[m] = mfma16(a0l, b0h, acc[m]);
            acc[m] = mfma16(a0h, b0l, acc[m]);
            acc[m] = mfma16(a1h, b1h, acc[m]);
            acc[m] = mfma16(a1l, b1h, acc[m]);
            acc[m] = mfma16(a1h, b1l, acc[m]);
        }
    }

    // relu + park C1 in the wave's private LDS slice (phase-C swizzle).
#pragma unroll
    for (int m = 0; m < 4; ++m) {
        int q = 4 * m + g;
        hb4[nt * 16 + (q ^ l15)] = make_float4(
            fmaxf(acc[m][0], 0.f), fmaxf(acc[m][1], 0.f),
            fmaxf(acc[m][2], 0.f), fmaxf(acc[m][3], 0.f));
    }
    // (no barrier: wave-private slice)

    // ---- matvec2: B2 = H2^T rebuilt from LDS, hi/lo split.
    f16x8 b2h[2], b2l[2];
#pragma unroll
    for (int ks = 0; ks < 2; ++ks) {
        int q0 = 8 * ks + 2 * g;
        float4 u0 = hb4[nt * 16 + ((q0 + 0) ^ l15)];
        float4 u1 = hb4[nt * 16 + ((q0 + 1) ^ l15)];
        float v[8] = {u0.x, u0.y, u0.z, u0.w, u1.x, u1.y, u1.z, u1.w};
#pragma unroll
        for (int j = 0; j < 8; ++j) {
            half_t h = (half_t)v[j];
            b2h[ks][j] = h;
            b2l[ks][j] = (half_t)(v[j] - (float)h);
        }
    }
    f32x4 acc2[4];
#pragma unroll
    for (int m = 0; m < 4; ++m) {
        float4 bv = *(const float4*)(bb + 16 * m + 4 * g);
        acc2[m][0] = bv.x; acc2[m][1] = bv.y; acc2[m][2] = bv.z; acc2[m][3] = bv.w;
    }
#pragma unroll
    for (int m = 0; m < 4; ++m) {
#pragma unroll
        for (int ks = 0; ks < 2; ++ks) {
            f16x8 ah = *(const f16x8*)(wf2 + (size_t)((m * 4 + ks * 2 + 0) * 64 + lane) * 8);
            f16x8 al = *(const f16x8*)(wf2 + (size_t)((m * 4 + ks * 2 + 1) * 64 + lane) * 8);
            acc2[m] = mfma16(ah, b2h[ks], acc2[m]);
            acc2[m] = mfma16(al, b2h[ks], acc2[m]);
            acc2[m] = mfma16(ah, b2l[ks], acc2[m]);
        }
    }
    // relu + write C2 in the phase-C layout (wave-private slice)
#pragma unroll
    for (int m = 0; m < 4; ++m) {
        int q = 4 * m + g;
        hb4[nt * 16 + (q ^ l15)] = make_float4(
            fmaxf(acc2[m][0], 0.f), fmaxf(acc2[m][1], 0.f),
            fmaxf(acc2[m][2], 0.f), fmaxf(acc2[m][3], 0.f));
    }

    // ---- phase C: fp16 store + BN partial stats (wave-private reads) ----
    {
        int q = lane & 15;          // channel quad
        int ng = lane >> 4;         // node subgroup
        int base_nt = wv * 16;
        float4 bs = make_float4(0, 0, 0, 0), bq = make_float4(0, 0, 0, 0);
#pragma unroll
        for (int s2 = 0; s2 < 4; ++s2) {
            int nt2 = base_nt + s2 * 4 + ng;
            int n = n0 + nt2;
            if (n < N) {
                float4 v = hb4[nt2 * 16 + (q ^ (nt2 & 15))];
                ushort4 o;
                o.x = f2h(v.x); o.y = f2h(v.y); o.z = f2h(v.z); o.w = f2h(v.w);
                *(ushort4*)(vout + (size_t)n * 64 + q * 4) = o;
                bs.x += v.x; bs.y += v.y; bs.z += v.z; bs.w += v.w;
                bq.x += v.x * v.x; bq.y += v.y * v.y;
                bq.z += v.z * v.z; bq.w += v.w * v.w;
            }
        }
#pragma unroll
        for (int off = 16; off < 64; off <<= 1) {
            bs.x += __shfl_xor(bs.x, off); bs.y += __shfl_xor(bs.y, off);
            bs.z += __shfl_xor(bs.z, off); bs.w += __shfl_xor(bs.w, off);
            bq.x += __shfl_xor(bq.x, off); bq.y += __shfl_xor(bq.y, off);
            bq.z += __shfl_xor(bq.z, off); bq.w += __shfl_xor(bq.w, off);
        }
        if (ng == 0) { bnS[wv][q] = bs; bnQ[wv][q] = bq; }
        __syncthreads();
        if (tid < 16) {
            float4 s4 = bnS[0][tid], q4 = bnQ[0][tid];
#pragma unroll
            for (int w2 = 1; w2 < 4; ++w2) {
                float4 t = bnS[w2][tid];
                s4.x += t.x; s4.y += t.y; s4.z += t.z; s4.w += t.w;
                float4 u = bnQ[w2][tid];
                q4.x += u.x; q4.y += u.y; q4.z += u.z; q4.w += u.w;
            }
            float* bkt = bnpart + (size_t)(blockIdx.x & (BNBKT - 1)) * 128;
            atomicAdd(&bkt[tid * 4 + 0], s4.x);
            atomicAdd(&bkt[tid * 4 + 1], s4.y);
            atomicAdd(&bkt[tid * 4 + 2], s4.z);
            atomicAdd(&bkt[tid * 4 + 3], s4.w);
            atomicAdd(&bkt[64 + tid * 4 + 0], q4.x);
            atomicAdd(&bkt[64 + tid * 4 + 1], q4.y);
            atomicAdd(&bkt[64 + tid * 4 + 2], q4.z);
            atomicAdd(&bkt[64 + tid * 4 + 3], q4.w);
        }
    }
}

// Standalone pool + BN finalize for the LAST layer's output.
__global__ __launch_bounds__(256) void k_pool_bn(
        const unsigned short* __restrict__ vb, const int* __restrict__ gstart,
        float* __restrict__ Sg,
        const float* __restrict__ bnpart, const float* __restrict__ gamma,
        const float* __restrict__ beta, float* __restrict__ a_out,
        float* __restrict__ b_out, int N, int Gn, int nbp) {
    if ((int)blockIdx.x == nbp) {
        bn_finalize(bnpart, gamma, beta, a_out, b_out, N);
        return;
    }
    int lane = threadIdx.x & 63, wv = threadIdx.x >> 6;
    int g = blockIdx.x * 4 + wv;
    if (g >= Gn) return;
    int sub = lane >> 4, q = lane & 15;
    int s = gstart[g], e = gstart[g + 1];
    float4 a0 = make_float4(0, 0, 0, 0), a1 = make_float4(0, 0, 0, 0);
    float4 a2 = make_float4(0, 0, 0, 0), a3 = make_float4(0, 0, 0, 0);
    int eb = s;
    for (; eb + 16 <= e; eb += 16) {
        ushort4 u0 = *(const ushort4*)(vb + (size_t)(eb + 0 + sub) * 64 + q * 4);
        ushort4 u1 = *(const ushort4*)(vb + (size_t)(eb + 4 + sub) * 64 + q * 4);
        ushort4 u2 = *(const ushort4*)(vb + (size_t)(eb + 8 + sub) * 64 + q * 4);
        ushort4 u3 = *(const ushort4*)(vb + (size_t)(eb + 12 + sub) * 64 + q * 4);
        a0.x += h2f(u0.x); a0.y += h2f(u0.y); a0.z += h2f(u0.z); a0.w += h2f(u0.w);
        a1.x += h2f(u1.x); a1.y += h2f(u1.y); a1.z += h2f(u1.z); a1.w += h2f(u1.w);
        a2.x += h2f(u2.x); a2.y += h2f(u2.y); a2.z += h2f(u2.z); a2.w += h2f(u2.w);
        a3.x += h2f(u3.x); a3.y += h2f(u3.y); a3.z += h2f(u3.z); a3.w += h2f(u3.w);
    }
    for (; eb + 4 <= e; eb += 4) {
        ushort4 u0 = *(const ushort4*)(vb + (size_t)(eb + sub) * 64 + q * 4);
        a0.x += h2f(u0.x); a0.y += h2f(u0.y); a0.z += h2f(u0.z); a0.w += h2f(u0.w);
    }
    if (eb + sub < e) {
        ushort4 u0 = *(const ushort4*)(vb + (size_t)(eb + sub) * 64 + q * 4);
        a1.x += h2f(u0.x); a1.y += h2f(u0.y); a1.z += h2f(u0.z); a1.w += h2f(u0.w);
    }
    float4 t;
    t.x = (a0.x + a1.x) + (a2.x + a3.x);
    t.y = (a0.y + a1.y) + (a2.y + a3.y);
    t.z = (a0.z + a1.z) + (a2.z + a3.z);
    t.w = (a0.w + a1.w) + (a2.w + a3.w);
#pragma unroll
    for (int off = 16; off < 64; off <<= 1) {
        t.x += __shfl_xor(t.x, off); t.y += __shfl_xor(t.y, off);
        t.z += __shfl_xor(t.z, off); t.w += __shfl_xor(t.w, off);
    }
    if (sub == 0) {
        *(float4*)(Sg + (size_t)g * 64 + q * 4) = t;
    }
}

// Head: z[g,320] = concat_l (a_l*S_l[g] + b_l*cnt[g]); out = relu(z@fc1+b)@fc2+b
__global__ __launch_bounds__(256) void k_final(
        const float* __restrict__ S, const float* __restrict__ ab,
        const int* __restrict__ cntg,
        const float* __restrict__ fc1W, const float* __restrict__ fc1b,
        const float* __restrict__ fc2W, const float* __restrict__ fc2b,
        float* __restrict__ out, int G) {
    __shared__ float zbuf[4][320];
    int tid = threadIdx.x;
    int lane = tid & 63, wv = tid >> 6;
    int g = blockIdx.x * 4 + wv;
    if (g >= G) return;
    float cf = (float)cntg[g];
#pragma unroll
    for (int l = 0; l < 5; ++l) {
        float a = ab[l * 128 + lane];
        float b = ab[l * 128 + 64 + lane];
        zbuf[wv][l * 64 + lane] = a * S[((size_t)l * G + g) * 64 + lane] + b * cf;
    }
    float acc = fc1b[lane];
    for (int k = 0; k < 320; ++k) acc += zbuf[wv][k] * fc1W[k * 64 + lane];
    float t = fmaxf(acc, 0.f);
    float r = t * fc2W[lane];
#pragma unroll
    for (int off = 32; off >= 1; off >>= 1) r += __shfl_xor(r, off);
    if (lane == 0) out[g] = r + fc2b[0];
}

extern "C" void kernel_launch(void* const* d_in, const int* in_sizes, int n_in,
                              void* d_out, int out_size, void* d_ws, size_t ws_size,
                              hipStream_t stream) {
    const float* x    = (const float*)d_in[0];
    const int*   ei   = (const int*)d_in[1];
    const int*   batch= (const int*)d_in[2];
    const float* W1a  = (const float*)d_in[3];
    const float* b1a  = (const float*)d_in[4];
    const float* W1b  = (const float*)d_in[5];
    const float* b1b  = (const float*)d_in[6];
    const float* Wa   = (const float*)d_in[7];
    const float* ba   = (const float*)d_in[8];
    const float* Wb   = (const float*)d_in[9];
    const float* bb   = (const float*)d_in[10];
    const float* gamma= (const float*)d_in[11];
    const float* beta = (const float*)d_in[12];
    const float* fc1W = (const float*)d_in[13];
    const float* fc1b = (const float*)d_in[14];
    const float* fc2W = (const float*)d_in[15];
    const float* fc2b = (const float*)d_in[16];

    const int N = in_sizes[2];
    const int E = in_sizes[1] / 2;
    const int G = out_size;
    const int* srcp = ei;
    const int* dstp = ei + E;

    char* p = (char*)d_ws;
    auto alloc = [&](size_t bytes) {
        char* r = p;
        p += (bytes + 255) & ~size_t(255);
        return r;
    };
    unsigned short* aggh = (unsigned short*)alloc((size_t)N * 64 * 2);
    unsigned short* vb   = (unsigned short*)alloc((size_t)N * 64 * 2);
    int*   col    = (int*)  alloc((size_t)N * DEGCAP * 4);
    int*   rank_  = (int*)  alloc((size_t)E * 4);
    unsigned short* x16h = (unsigned short*)alloc((size_t)N * 16 * 2);
    float* h16    = (float*)alloc((size_t)N * 16 * 4);
    int*   gstart = (int*)  alloc((size_t)(G + 1) * 4);
    float* ab     = (float*)alloc(5 * 128 * 4);
    half_t* wfrag = (half_t*)alloc((size_t)10 * 8192 * 2);
    // ---- zeroed region (single memset) ----
    char*  z0     = p;
    int*   cntn   = (int*)  alloc((size_t)N * 4);
    int*   cntg   = (int*)  alloc((size_t)G * 4);
    float* S      = (float*)alloc((size_t)5 * G * 64 * 4);
    float* bnpart = (float*)alloc((size_t)5 * BNBKT * 128 * 4);
    size_t zbytes = (size_t)(p - z0);

    hipMemsetAsync(z0, 0, zbytes, stream);

    int nb_e = (E + 255) / 256;
    int nb_n = (N + 255) / 256;
    k_histw<<<nb_e + 10, 256, 0, stream>>>(dstp, E, cntn, rank_,
                                           W1a, W1b, Wa, Wb, wfrag);
    k_fill<<<nb_e, 256, 0, stream>>>(srcp, dstp, rank_, E, col);
    k_prep<<<nb_n, 256, 0, stream>>>(x, x16h, batch, cntg, N);

    int nb_node = (N + 3) / 4;
    int nb_tile = (N + 63) / 64;
    int nbp = (G + 3) / 4;
    const size_t FR = 8192;   // halfs per packed matrix
    const size_t BN = (size_t)BNBKT * 128;  // floats per layer of bnpart

    // Layer 1: 16-dim fp16 gather (+ scang extra block), then mlp<FIRST>
    k_gather16<<<nb_node + 1, 256, 0, stream>>>(x16h, h16, cntn, col, N,
                                                nb_node, cntg, G, gstart);
    k_mlp<true><<<nb_tile, 256, 0, stream>>>(h16, vb,
        wfrag + 0 * FR, b1a, wfrag + 1 * FR, b1b, bnpart,
        ab, cntn, N);

    // Layers 2-5: merged [pool(l) || gather(l+1)] then mlp (affine in mlp)
    for (int l = 0; l < 4; ++l) {
        k_pgather<<<nbp + 1 + nb_node, 256, 0, stream>>>(vb, gstart,
            S + (size_t)l * G * 64,
            bnpart + (size_t)l * BN,
            gamma + l * 64, beta + l * 64,
            ab + l * 128, ab + l * 128 + 64,
            aggh, cntn, col, N, G, nbp);
        k_mlp<false><<<nb_tile, 256, 0, stream>>>(aggh, vb,
            wfrag + (size_t)(2 + l) * FR, ba + l * 64,
            wfrag + (size_t)(6 + l) * FR, bb + l * 64,
            bnpart + (size_t)(l + 1) * BN,
            ab + l * 128, cntn, N);
    }

    // Last layer's pooling + BN finalize, then head.
    k_pool_bn<<<nbp + 1, 256, 0, stream>>>(vb, gstart,
        S + (size_t)4 * G * 64, bnpart + (size_t)4 * BN,
        gamma + 4 * 64, beta + 4 * 64,
        ab + 4 * 128, ab + 4 * 128 + 64, N, G, nbp);
    k_final<<<(G + 3) / 4, 256, 0, stream>>>(S, ab, cntg, fc1W, fc1b, fc2W, fc2b,
                                             (float*)d_out, G);
}

// Round 13
// 608.005 us; speedup vs baseline: 1.0575x; 1.0575x over previous
//
#include <hip/hip_runtime.h>
#include <hip/hip_fp16.h>

// ---------------------------------------------------------------------------
// GIN (5 layers) + BN + graph pooling + MLP head.
// R28: exact resubmit of R26 (measured 608.9us, session best) to separate
//      two confounded hypotheses for R27's 643: (a) R27's changes (split
//      fill/prep + BNBKT 256) cost ~34us; (b) 609 was container luck and
//      the structure's true plateau is ~640. No new changes: attribution
//      before optimization. If ~609 reproduces -> R27 harmful, keep this.
//      If ~640 -> plateau confirmed; all components at measured floors
//      (hist 67 = atomic pipe; fill ~75 = padded-scatter write-allocate;
//      gather 50-55 = random-128B-row fabric floor; mlp: two structural
//      attacks failed; pool hidden under gather).
// R26: padded-bucket CSR (col[d*64+rank], NO scan), pipelined histw -> 
//      fillprep; scang folded into gather16. 13 dispatches.
// R24: BN-affine fold (gather stores raw sums; mlp applies a*s+b*(1+deg));
//      pool_bn merged into gather dispatch (k_pgather), off the chain.
// Lessons: atomics and dependent scatters must not share a kernel (R25);
//      never one-block a >100KB reduction in a short dispatch (R22); don't
//      attack unmeasured inferred costs (R22, R27); gather = fabric floor,
//      1 wave = 1 node; don't fuse INTO gather; hist's atomic pipe
//      tolerates no co-tenants.
// R16: per-wave 16-node C^T MFMA tiles, fp32-equiv hi/lo weight split.
// ---------------------------------------------------------------------------

#define DEGCAP 64

typedef _Float16 half_t;
typedef half_t f16x8 __attribute__((ext_vector_type(8)));
typedef float f32x4 __attribute__((ext_vector_type(4)));

__device__ __forceinline__ unsigned short f2h(float f) {
    return __half_as_ushort(__float2half_rn(f));
}
__device__ __forceinline__ float h2f(unsigned short s) {
    return __half2float(__ushort_as_half(s));
}
__device__ __forceinline__ f32x4 mfma16(f16x8 a, f16x8 b, f32x4 c) {
    return __builtin_amdgcn_mfma_f32_16x16x32_f16(a, b, c, 0, 0, 0);
}

// Merged: blocks [0,10) pack W^T into MFMA A-fragments (hi/lo split);
// blocks [10,..) edge histogram + rank (atomic returns slot).
__global__ __launch_bounds__(256) void k_histw(const int* __restrict__ dst, int E,
        int* __restrict__ cnt_node, int* __restrict__ rank_,
        const float* __restrict__ W1a, const float* __restrict__ W1b,
        const float* __restrict__ Wa, const float* __restrict__ Wb,
        half_t* __restrict__ wout) {
    if ((int)blockIdx.x < 10) {
        int mat = blockIdx.x;      // 0=W1a 1=W1b 2..5=Wa[l] 6..9=Wb[l]
        const float* W; int K;
        if (mat == 0)      { W = W1a; K = 11; }
        else if (mat == 1) { W = W1b; K = 64; }
        else if (mat < 6)  { W = Wa + (mat - 2) * 4096; K = 64; }
        else               { W = Wb + (mat - 6) * 4096; K = 64; }
        int lane = threadIdx.x & 63, m = threadIdx.x >> 6;
        int row = 16 * m + (lane & 15);
#pragma unroll
        for (int ks = 0; ks < 2; ++ks) {
            f16x8 hi, lo;
#pragma unroll
            for (int j = 0; j < 8; ++j) {
                int k = 32 * ks + (lane >> 4) * 8 + j;
                float w = (k < K) ? W[k * 64 + row] : 0.f;
                half_t h = (half_t)w;
                hi[j] = h;
                lo[j] = (half_t)(w - (float)h);
            }
            size_t base = ((size_t)mat * 4 + m) * 4 + (size_t)ks * 2;
            *(f16x8*)(wout + ((base + 0) * 64 + lane) * 8) = hi;
            *(f16x8*)(wout + ((base + 1) * 64 + lane) * 8) = lo;
        }
    } else {
        int i = ((int)blockIdx.x - 10) * 256 + threadIdx.x;
        if (i < E) rank_[i] = atomicAdd(&cnt_node[dst[i]], 1);
    }
}

// Merged: blocks [0,nb_n) node prep (x -> fp16 padded 16ch, graph counts);
// blocks [nb_n,..) CSR fill into padded buckets (pure scatter, no atomics).
__global__ __launch_bounds__(256) void k_fillprep(
        const int* __restrict__ src, const int* __restrict__ dst,
        const int* __restrict__ rank_, int E, int* __restrict__ col,
        const float* __restrict__ x, unsigned short* __restrict__ x16h,
        const int* __restrict__ batch, int* __restrict__ cnt_graph, int N,
        int nb_n) {
    if ((int)blockIdx.x < nb_n) {
        int i = blockIdx.x * 256 + threadIdx.x;
        if (i < N) {
            atomicAdd(&cnt_graph[batch[i]], 1);
#pragma unroll
            for (int k = 0; k < 11; ++k) x16h[i * 16 + k] = f2h(x[i * 11 + k]);
#pragma unroll
            for (int k = 11; k < 16; ++k) x16h[i * 16 + k] = 0;
        }
    } else {
        int e = ((int)blockIdx.x - nb_n) * 256 + threadIdx.x;
        if (e < E) {
            __builtin_nontemporal_store(src[e],
                &col[(size_t)dst[e] * DEGCAP + rank_[e]]);
        }
    }
}

// Layer-1 gather in padded 11->16 dim fp16 space: wave = 1 node, 4 edges per
// step (16 lanes per edge), 4-deep -> 16 edges in flight. fp32 out.
// Extra block (blockIdx.x == nb_node): exclusive scan cntg -> gstart.
__global__ __launch_bounds__(256, 8) void k_gather16(
        const unsigned short* __restrict__ x16h, float* __restrict__ h16,
        const int* __restrict__ cnt, const int* __restrict__ col, int N,
        int nb_node, const int* __restrict__ cntg, int Gn,
        int* __restrict__ gstart) {
    if ((int)blockIdx.x == nb_node) {
        __shared__ int sd[256];
        int t = threadIdx.x;
        int base = t * 4;
        int v0 = (base + 0 < Gn) ? cntg[base + 0] : 0;
        int v1 = (base + 1 < Gn) ? cntg[base + 1] : 0;
        int v2 = (base + 2 < Gn) ? cntg[base + 2] : 0;
        int v3 = (base + 3 < Gn) ? cntg[base + 3] : 0;
        int tsum = v0 + v1 + v2 + v3;
        sd[t] = tsum;
        __syncthreads();
        for (int off = 1; off < 256; off <<= 1) {
            int val = (t >= off) ? sd[t - off] : 0;
            __syncthreads();
            sd[t] += val;
            __syncthreads();
        }
        int excl = sd[t] - tsum;
        if (base + 0 < Gn) gstart[base + 0] = excl;
        if (base + 1 < Gn) gstart[base + 1] = excl + v0;
        if (base + 2 < Gn) gstart[base + 2] = excl + v0 + v1;
        if (base + 3 < Gn) gstart[base + 3] = excl + v0 + v1 + v2;
        if (t == 255) gstart[Gn] = sd[255];     // = N
        return;
    }
    int lane = threadIdx.x & 63, wv = threadIdx.x >> 6;
    int n = blockIdx.x * 4 + wv;
    if (n >= N) return;
    int sub = lane >> 4, c = lane & 15;
    int start = n * DEGCAP;
    int end = start + cnt[n];
    float s0 = 0.f, s1 = 0.f, s2 = 0.f, s3 = 0.f;
    int eb = start;
    for (; eb + 16 <= end; eb += 16) {
        int j0 = col[eb + sub];
        int j1 = col[eb + 4 + sub];
        int j2 = col[eb + 8 + sub];
        int j3 = col[eb + 12 + sub];
        s0 += h2f(x16h[(size_t)j0 * 16 + c]);
        s1 += h2f(x16h[(size_t)j1 * 16 + c]);
        s2 += h2f(x16h[(size_t)j2 * 16 + c]);
        s3 += h2f(x16h[(size_t)j3 * 16 + c]);
    }
    for (; eb + 4 <= end; eb += 4) {
        int j0 = col[eb + sub];
        s0 += h2f(x16h[(size_t)j0 * 16 + c]);
    }
    for (int e = eb + sub; e < end; e += 4) {
        s1 += h2f(x16h[(size_t)col[e] * 16 + c]);
    }
    float s = (s0 + s1) + (s2 + s3);
    s += __shfl_xor(s, 16);
    s += __shfl_xor(s, 32);
    if (lane < 16) {
        h16[(size_t)n * 16 + lane] = s + h2f(x16h[(size_t)n * 16 + lane]);
    }
}

// Merged pool + gather (layers 2-5). Blocks [0, nbp]: graph pooling of the
// JUST-WRITTEN vb (segment-sum, zero atomics) + BN finalize (block nbp).
// Blocks (nbp, ...): gather for the NEXT layer -- stores RAW sums (fp16),
// BN affine deferred to k_mlp (the R24 fold that makes these independent).
__global__ __launch_bounds__(256, 8) void k_pgather(
        const unsigned short* __restrict__ vb, const int* __restrict__ gstart,
        float* __restrict__ Sg,
        const float* __restrict__ bnpart, const float* __restrict__ gamma,
        const float* __restrict__ beta, float* __restrict__ a_out,
        float* __restrict__ b_out,
        unsigned short* __restrict__ aggh, const int* __restrict__ cnt,
        const int* __restrict__ col,
        int N, int Gn, int nbp) {
    if ((int)blockIdx.x <= nbp) {
        // ---- pool role ----
        if ((int)blockIdx.x == nbp) {
            int c = threadIdx.x;
            if (c < 64) {
                float s = 0.f, q = 0.f;
                for (int i = 0; i < 32; ++i) {
                    s += bnpart[i * 128 + c];
                    q += bnpart[i * 128 + 64 + c];
                }
                float invN = 1.0f / (float)N;
                float mu = s * invN;
                float var = q * invN - mu * mu;
                float ac = gamma[c] * rsqrtf(var + 1e-5f);
                a_out[c] = ac;
                b_out[c] = beta[c] - mu * ac;
            }
            return;
        }
        int lane = threadIdx.x & 63, wv = threadIdx.x >> 6;
        int g = blockIdx.x * 4 + wv;
        if (g >= Gn) return;
        int sub = lane >> 4, q = lane & 15;
        int s = gstart[g], e = gstart[g + 1];
        float4 a0 = make_float4(0, 0, 0, 0), a1 = make_float4(0, 0, 0, 0);
        float4 a2 = make_float4(0, 0, 0, 0), a3 = make_float4(0, 0, 0, 0);
        int eb = s;
        for (; eb + 16 <= e; eb += 16) {
            ushort4 u0 = *(const ushort4*)(vb + (size_t)(eb + 0 + sub) * 64 + q * 4);
            ushort4 u1 = *(const ushort4*)(vb + (size_t)(eb + 4 + sub) * 64 + q * 4);
            ushort4 u2 = *(const ushort4*)(vb + (size_t)(eb + 8 + sub) * 64 + q * 4);
            ushort4 u3 = *(const ushort4*)(vb + (size_t)(eb + 12 + sub) * 64 + q * 4);
            a0.x += h2f(u0.x); a0.y += h2f(u0.y); a0.z += h2f(u0.z); a0.w += h2f(u0.w);
            a1.x += h2f(u1.x); a1.y += h2f(u1.y); a1.z += h2f(u1.z); a1.w += h2f(u1.w);
            a2.x += h2f(u2.x); a2.y += h2f(u2.y); a2.z += h2f(u2.z); a2.w += h2f(u2.w);
            a3.x += h2f(u3.x); a3.y += h2f(u3.y); a3.z += h2f(u3.z); a3.w += h2f(u3.w);
        }
        for (; eb + 4 <= e; eb += 4) {
            ushort4 u0 = *(const ushort4*)(vb + (size_t)(eb + sub) * 64 + q * 4);
            a0.x += h2f(u0.x); a0.y += h2f(u0.y); a0.z += h2f(u0.z); a0.w += h2f(u0.w);
        }
        if (eb + sub < e) {
            ushort4 u0 = *(const ushort4*)(vb + (size_t)(eb + sub) * 64 + q * 4);
            a1.x += h2f(u0.x); a1.y += h2f(u0.y); a1.z += h2f(u0.z); a1.w += h2f(u0.w);
        }
        float4 t;
        t.x = (a0.x + a1.x) + (a2.x + a3.x);
        t.y = (a0.y + a1.y) + (a2.y + a3.y);
        t.z = (a0.z + a1.z) + (a2.z + a3.z);
        t.w = (a0.w + a1.w) + (a2.w + a3.w);
#pragma unroll
        for (int off = 16; off < 64; off <<= 1) {
            t.x += __shfl_xor(t.x, off); t.y += __shfl_xor(t.y, off);
            t.z += __shfl_xor(t.z, off); t.w += __shfl_xor(t.w, off);
        }
        if (sub == 0) {
            *(float4*)(Sg + (size_t)g * 64 + q * 4) = t;
        }
        return;
    }
    // ---- gather role: raw sums, no BN affine ----
    int bid = (int)blockIdx.x - nbp - 1;
    int lane = threadIdx.x & 63, wv = threadIdx.x >> 6;
    int n = bid * 4 + wv;
    if (n >= N) return;
    int start = n * DEGCAP;
    int end = start + cnt[n];
    float s[16];
#pragma unroll
    for (int u = 0; u < 16; ++u) s[u] = 0.f;
    s[0] = h2f(vb[(size_t)n * 64 + lane]);
    int e = start;
    for (; e + 16 <= end; e += 16) {
        int j[16];
#pragma unroll
        for (int u = 0; u < 16; ++u) j[u] = col[e + u];
#pragma unroll
        for (int u = 0; u < 16; ++u)
            s[u] += h2f(vb[(size_t)j[u] * 64 + lane]);
    }
    for (; e + 4 <= end; e += 4) {
        int j0 = col[e + 0], j1 = col[e + 1], j2 = col[e + 2], j3 = col[e + 3];
        s[0] += h2f(vb[(size_t)j0 * 64 + lane]);
        s[1] += h2f(vb[(size_t)j1 * 64 + lane]);
        s[2] += h2f(vb[(size_t)j2 * 64 + lane]);
        s[3] += h2f(vb[(size_t)j3 * 64 + lane]);
    }
    for (; e < end; ++e) s[0] += h2f(vb[(size_t)col[e] * 64 + lane]);
#pragma unroll
    for (int u = 8; u > 0; u >>= 1)
#pragma unroll
        for (int v2 = 0; v2 < u; ++v2) s[v2] += s[v2 + u];
    aggh[(size_t)n * 64 + lane] = f2h(s[0]);
}

// MLP: one block = one 64-node tile, 4 waves x 16 nodes each. Both matvecs
// via mfma_f32_16x16x32_f16 on C^T = W^T x H^T (wave-private, barrier-free).
// FIRST=false: input = RAW sums; BN affine v = a*s + b*(1+deg) applied here
// in fp32 (deg = cnt[node]), hi/lo split into the B-operand.
// Phase C: fp16 store + block-aggregated BN partials (128 atomics, 32 bkts).
template <bool FIRST>
__global__ __launch_bounds__(256, 4) void k_mlp(
        const void* __restrict__ aggp, unsigned short* __restrict__ vout,
        const half_t* __restrict__ wf1, const float* __restrict__ ba,
        const half_t* __restrict__ wf2, const float* __restrict__ bb,
        float* __restrict__ bnpart,
        const float* __restrict__ ab_prev, const int* __restrict__ cnt,
        int N) {
    __shared__ float hb[64 * 64];
    __shared__ float4 bnS[4][16], bnQ[4][16];
    float4* hb4 = (float4*)hb;
    const int tid = threadIdx.x;
    const int lane = tid & 63;
    const int wv = tid >> 6;
    const int n0 = blockIdx.x * 64;
    const int l15 = lane & 15;
    const int g = lane >> 4;
    const int nt = wv * 16 + l15;          // tile-local node (B-operand col)
    const int node = n0 + nt;

    // ---- matvec1: C1^T[ch_out][node]; bias folded into acc init.
    f32x4 acc[4];
#pragma unroll
    for (int m = 0; m < 4; ++m) {
        float4 bv = *(const float4*)(ba + 16 * m + 4 * g);
        acc[m][0] = bv.x; acc[m][1] = bv.y; acc[m][2] = bv.z; acc[m][3] = bv.w;
    }

    if (FIRST) {
        // B = H^T from h16 (fp32 Nx16), hi/lo split (exact).
        f16x8 bhi, blo;
#pragma unroll
        for (int j = 0; j < 8; ++j) { bhi[j] = (half_t)0; blo[j] = (half_t)0; }
        if (g < 2 && node < N) {
            const float* h16 = (const float*)aggp;
            float4 v0 = *(const float4*)(h16 + (size_t)node * 16 + g * 8);
            float4 v1 = *(const float4*)(h16 + (size_t)node * 16 + g * 8 + 4);
            float v[8] = {v0.x, v0.y, v0.z, v0.w, v1.x, v1.y, v1.z, v1.w};
#pragma unroll
            for (int j = 0; j < 8; ++j) {
                half_t h = (half_t)v[j];
                bhi[j] = h;
                blo[j] = (half_t)(v[j] - (float)h);
            }
        }
#pragma unroll
        for (int m = 0; m < 4; ++m) {
            f16x8 ah = *(const f16x8*)(wf1 + (size_t)((m * 4 + 0) * 64 + lane) * 8);
            f16x8 al = *(const f16x8*)(wf1 + (size_t)((m * 4 + 1) * 64 + lane) * 8);
            acc[m] = mfma16(ah, bhi, acc[m]);
            acc[m] = mfma16(al, bhi, acc[m]);
            acc[m] = mfma16(ah, blo, acc[m]);
        }
    } else {
        // B = affine(raw sums): v = a*s + b*(1+deg), hi/lo split.
        f16x8 b0h, b0l, b1h, b1l;
#pragma unroll
        for (int j = 0; j < 8; ++j) {
            b0h[j] = (half_t)0; b0l[j] = (half_t)0;
            b1h[j] = (half_t)0; b1l[j] = (half_t)0;
        }
        if (node < N) {
            const half_t* ah16 = (const half_t*)aggp;
            f16x8 s0 = *(const f16x8*)(ah16 + (size_t)node * 64 + g * 8);
            f16x8 s1 = *(const f16x8*)(ah16 + (size_t)node * 64 + 32 + g * 8);
            float dd = (float)(1 + cnt[node]);
            float4 aA0 = *(const float4*)(ab_prev + g * 8);
            float4 aA1 = *(const float4*)(ab_prev + g * 8 + 4);
            float4 aB0 = *(const float4*)(ab_prev + 32 + g * 8);
            float4 aB1 = *(const float4*)(ab_prev + 32 + g * 8 + 4);
            float4 bA0 = *(const float4*)(ab_prev + 64 + g * 8);
            float4 bA1 = *(const float4*)(ab_prev + 64 + g * 8 + 4);
            float4 bB0 = *(const float4*)(ab_prev + 96 + g * 8);
            float4 bB1 = *(const float4*)(ab_prev + 96 + g * 8 + 4);
            float aa0[8] = {aA0.x, aA0.y, aA0.z, aA0.w, aA1.x, aA1.y, aA1.z, aA1.w};
            float aa1[8] = {aB0.x, aB0.y, aB0.z, aB0.w, aB1.x, aB1.y, aB1.z, aB1.w};
            float cc0[8] = {bA0.x, bA0.y, bA0.z, bA0.w, bA1.x, bA1.y, bA1.z, bA1.w};
            float cc1[8] = {bB0.x, bB0.y, bB0.z, bB0.w, bB1.x, bB1.y, bB1.z, bB1.w};
#pragma unroll
            for (int j = 0; j < 8; ++j) {
                float v0 = fmaf(aa0[j], (float)s0[j], cc0[j] * dd);
                half_t h0 = (half_t)v0;
                b0h[j] = h0; b0l[j] = (half_t)(v0 - (float)h0);
                float v1 = fmaf(aa1[j], (float)s1[j], cc1[j] * dd);
                half_t h1 = (half_t)v1;
                b1h[j] = h1; b1l[j] = (half_t)(v1 - (float)h1);
            }
        }
#pragma unroll
        for (int m = 0; m < 4; ++m) {
            f16x8 a0h = *(const f16x8*)(wf1 + (size_t)((m * 4 + 0) * 64 + lane) * 8);
            f16x8 a0l = *(const f16x8*)(wf1 + (size_t)((m * 4 + 1) * 64 + lane) * 8);
            f16x8 a1h = *(const f16x8*)(wf1 + (size_t)((m * 4 + 2) * 64 + lane) * 8);
            f16x8 a1l = *(const f16x8*)(wf1 + (size_t)((m * 4 + 3) * 64 + lane) * 8);
            acc[m] = mfma16(a0h, b0h, acc[m]);
            acc[m] = mfma16(a0l, b0h, acc[m]);
            acc[m] = mfma16(a0h, b0l, acc[m]);
            acc[m] = mfma16(a1h, b1h, acc[m]);
            acc[m] = mfma16(a1l, b1h, acc[m]);
            acc[m] = mfma16(a1h, b1l, acc[m]);
        }
    }

    // relu + park C1 in the wave's private LDS slice (phase-C swizzle).
#pragma unroll
    for (int m = 0; m < 4; ++m) {
        int q = 4 * m + g;
        hb4[nt * 16 + (q ^ l15)] = make_float4(
            fmaxf(acc[m][0], 0.f), fmaxf(acc[m][1], 0.f),
            fmaxf(acc[m][2], 0.f), fmaxf(acc[m][3], 0.f));
    }
    // (no barrier: wave-private slice)

    // ---- matvec2: B2 = H2^T rebuilt from LDS, hi/lo split.
    f16x8 b2h[2], b2l[2];
#pragma unroll
    for (int ks = 0; ks < 2; ++ks) {
        int q0 = 8 * ks + 2 * g;
        float4 u0 = hb4[nt * 16 + ((q0 + 0) ^ l15)];
        float4 u1 = hb4[nt * 16 + ((q0 + 1) ^ l15)];
        float v[8] = {u0.x, u0.y, u0.z, u0.w, u1.x, u1.y, u1.z, u1.w};
#pragma unroll
        for (int j = 0; j < 8; ++j) {
            half_t h = (half_t)v[j];
            b2h[ks][j] = h;
            b2l[ks][j] = (half_t)(v[j] - (float)h);
        }
    }
    f32x4 acc2[4];
#pragma unroll
    for (int m = 0; m < 4; ++m) {
        float4 bv = *(const float4*)(bb + 16 * m + 4 * g);
        acc2[m][0] = bv.x; acc2[m][1] = bv.y; acc2[m][2] = bv.z; acc2[m][3] = bv.w;
    }
#pragma unroll
    for (int m = 0; m < 4; ++m) {
#pragma unroll
        for (int ks = 0; ks < 2; ++ks) {
            f16x8 ah = *(const f16x8*)(wf2 + (size_t)((m * 4 + ks * 2 + 0) * 64 + lane) * 8);
            f16x8 al = *(const f16x8*)(wf2 + (size_t)((m * 4 + ks * 2 + 1) * 64 + lane) * 8);
            acc2[m] = mfma16(ah, b2h[ks], acc2[m]);
            acc2[m] = mfma16(al, b2h[ks], acc2[m]);
            acc2[m] = mfma16(ah, b2l[ks], acc2[m]);
        }
    }
    // relu + write C2 in the phase-C layout (wave-private slice)
#pragma unroll
    for (int m = 0; m < 4; ++m) {
        int q = 4 * m + g;
        hb4[nt * 16 + (q ^ l15)] = make_float4(
            fmaxf(acc2[m][0], 0.f), fmaxf(acc2[m][1], 0.f),
            fmaxf(acc2[m][2], 0.f), fmaxf(acc2[m][3], 0.f));
    }

    // ---- phase C: fp16 store + BN partial stats (wave-private reads) ----
    {
        int q = lane & 15;          // channel quad
        int ng = lane >> 4;         // node subgroup
        int base_nt = wv * 16;
        float4 bs = make_float4(0, 0, 0, 0), bq = make_float4(0, 0, 0, 0);
#pragma unroll
        for (int s2 = 0; s2 < 4; ++s2) {
            int nt2 = base_nt + s2 * 4 + ng;
            int n = n0 + nt2;
            if (n < N) {
                float4 v = hb4[nt2 * 16 + (q ^ (nt2 & 15))];
                ushort4 o;
                o.x = f2h(v.x); o.y = f2h(v.y); o.z = f2h(v.z); o.w = f2h(v.w);
                *(ushort4*)(vout + (size_t)n * 64 + q * 4) = o;
                bs.x += v.x; bs.y += v.y; bs.z += v.z; bs.w += v.w;
                bq.x += v.x * v.x; bq.y += v.y * v.y;
                bq.z += v.z * v.z; bq.w += v.w * v.w;
            }
        }
#pragma unroll
        for (int off = 16; off < 64; off <<= 1) {
            bs.x += __shfl_xor(bs.x, off); bs.y += __shfl_xor(bs.y, off);
            bs.z += __shfl_xor(bs.z, off); bs.w += __shfl_xor(bs.w, off);
            bq.x += __shfl_xor(bq.x, off); bq.y += __shfl_xor(bq.y, off);
            bq.z += __shfl_xor(bq.z, off); bq.w += __shfl_xor(bq.w, off);
        }
        if (ng == 0) { bnS[wv][q] = bs; bnQ[wv][q] = bq; }
        __syncthreads();
        if (tid < 16) {
            float4 s4 = bnS[0][tid], q4 = bnQ[0][tid];
#pragma unroll
            for (int w2 = 1; w2 < 4; ++w2) {
                float4 t = bnS[w2][tid];
                s4.x += t.x; s4.y += t.y; s4.z += t.z; s4.w += t.w;
                float4 u = bnQ[w2][tid];
                q4.x += u.x; q4.y += u.y; q4.z += u.z; q4.w += u.w;
            }
            float* bkt = bnpart + (blockIdx.x & 31) * 128;
            atomicAdd(&bkt[tid * 4 + 0], s4.x);
            atomicAdd(&bkt[tid * 4 + 1], s4.y);
            atomicAdd(&bkt[tid * 4 + 2], s4.z);
            atomicAdd(&bkt[tid * 4 + 3], s4.w);
            atomicAdd(&bkt[64 + tid * 4 + 0], q4.x);
            atomicAdd(&bkt[64 + tid * 4 + 1], q4.y);
            atomicAdd(&bkt[64 + tid * 4 + 2], q4.z);
            atomicAdd(&bkt[64 + tid * 4 + 3], q4.w);
        }
    }
}

// Standalone pool + BN finalize for the LAST layer's output.
__global__ __launch_bounds__(256) void k_pool_bn(
        const unsigned short* __restrict__ vb, const int* __restrict__ gstart,
        float* __restrict__ Sg,
        const float* __restrict__ bnpart, const float* __restrict__ gamma,
        const float* __restrict__ beta, float* __restrict__ a_out,
        float* __restrict__ b_out, int N, int Gn, int nbp) {
    if ((int)blockIdx.x == nbp) {
        int c = threadIdx.x;
        if (c < 64) {
            float s = 0.f, q = 0.f;
            for (int i = 0; i < 32; ++i) {
                s += bnpart[i * 128 + c];
                q += bnpart[i * 128 + 64 + c];
            }
            float invN = 1.0f / (float)N;
            float mu = s * invN;
            float var = q * invN - mu * mu;
            float ac = gamma[c] * rsqrtf(var + 1e-5f);
            a_out[c] = ac;
            b_out[c] = beta[c] - mu * ac;
        }
        return;
    }
    int lane = threadIdx.x & 63, wv = threadIdx.x >> 6;
    int g = blockIdx.x * 4 + wv;
    if (g >= Gn) return;
    int sub = lane >> 4, q = lane & 15;
    int s = gstart[g], e = gstart[g + 1];
    float4 a0 = make_float4(0, 0, 0, 0), a1 = make_float4(0, 0, 0, 0);
    float4 a2 = make_float4(0, 0, 0, 0), a3 = make_float4(0, 0, 0, 0);
    int eb = s;
    for (; eb + 16 <= e; eb += 16) {
        ushort4 u0 = *(const ushort4*)(vb + (size_t)(eb + 0 + sub) * 64 + q * 4);
        ushort4 u1 = *(const ushort4*)(vb + (size_t)(eb + 4 + sub) * 64 + q * 4);
        ushort4 u2 = *(const ushort4*)(vb + (size_t)(eb + 8 + sub) * 64 + q * 4);
        ushort4 u3 = *(const ushort4*)(vb + (size_t)(eb + 12 + sub) * 64 + q * 4);
        a0.x += h2f(u0.x); a0.y += h2f(u0.y); a0.z += h2f(u0.z); a0.w += h2f(u0.w);
        a1.x += h2f(u1.x); a1.y += h2f(u1.y); a1.z += h2f(u1.z); a1.w += h2f(u1.w);
        a2.x += h2f(u2.x); a2.y += h2f(u2.y); a2.z += h2f(u2.z); a2.w += h2f(u2.w);
        a3.x += h2f(u3.x); a3.y += h2f(u3.y); a3.z += h2f(u3.z); a3.w += h2f(u3.w);
    }
    for (; eb + 4 <= e; eb += 4) {
        ushort4 u0 = *(const ushort4*)(vb + (size_t)(eb + sub) * 64 + q * 4);
        a0.x += h2f(u0.x); a0.y += h2f(u0.y); a0.z += h2f(u0.z); a0.w += h2f(u0.w);
    }
    if (eb + sub < e) {
        ushort4 u0 = *(const ushort4*)(vb + (size_t)(eb + sub) * 64 + q * 4);
        a1.x += h2f(u0.x); a1.y += h2f(u0.y); a1.z += h2f(u0.z); a1.w += h2f(u0.w);
    }
    float4 t;
    t.x = (a0.x + a1.x) + (a2.x + a3.x);
    t.y = (a0.y + a1.y) + (a2.y + a3.y);
    t.z = (a0.z + a1.z) + (a2.z + a3.z);
    t.w = (a0.w + a1.w) + (a2.w + a3.w);
#pragma unroll
    for (int off = 16; off < 64; off <<= 1) {
        t.x += __shfl_xor(t.x, off); t.y += __shfl_xor(t.y, off);
        t.z += __shfl_xor(t.z, off); t.w += __shfl_xor(t.w, off);
    }
    if (sub == 0) {
        *(float4*)(Sg + (size_t)g * 64 + q * 4) = t;
    }
}

// Head: z[g,320] = concat_l (a_l*S_l[g] + b_l*cnt[g]); out = relu(z@fc1+b)@fc2+b
__global__ __launch_bounds__(256) void k_final(
        const float* __restrict__ S, const float* __restrict__ ab,
        const int* __restrict__ cntg,
        const float* __restrict__ fc1W, const float* __restrict__ fc1b,
        const float* __restrict__ fc2W, const float* __restrict__ fc2b,
        float* __restrict__ out, int G) {
    __shared__ float zbuf[4][320];
    int tid = threadIdx.x;
    int lane = tid & 63, wv = tid >> 6;
    int g = blockIdx.x * 4 + wv;
    if (g >= G) return;
    float cf = (float)cntg[g];
#pragma unroll
    for (int l = 0; l < 5; ++l) {
        float a = ab[l * 128 + lane];
        float b = ab[l * 128 + 64 + lane];
        zbuf[wv][l * 64 + lane] = a * S[((size_t)l * G + g) * 64 + lane] + b * cf;
    }
    float acc = fc1b[lane];
    for (int k = 0; k < 320; ++k) acc += zbuf[wv][k] * fc1W[k * 64 + lane];
    float t = fmaxf(acc, 0.f);
    float r = t * fc2W[lane];
#pragma unroll
    for (int off = 32; off >= 1; off >>= 1) r += __shfl_xor(r, off);
    if (lane == 0) out[g] = r + fc2b[0];
}

extern "C" void kernel_launch(void* const* d_in, const int* in_sizes, int n_in,
                              void* d_out, int out_size, void* d_ws, size_t ws_size,
                              hipStream_t stream) {
    const float* x    = (const float*)d_in[0];
    const int*   ei   = (const int*)d_in[1];
    const int*   batch= (const int*)d_in[2];
    const float* W1a  = (const float*)d_in[3];
    const float* b1a  = (const float*)d_in[4];
    const float* W1b  = (const float*)d_in[5];
    const float* b1b  = (const float*)d_in[6];
    const float* Wa   = (const float*)d_in[7];
    const float* ba   = (const float*)d_in[8];
    const float* Wb   = (const float*)d_in[9];
    const float* bb   = (const float*)d_in[10];
    const float* gamma= (const float*)d_in[11];
    const float* beta = (const float*)d_in[12];
    const float* fc1W = (const float*)d_in[13];
    const float* fc1b = (const float*)d_in[14];
    const float* fc2W = (const float*)d_in[15];
    const float* fc2b = (const float*)d_in[16];

    const int N = in_sizes[2];
    const int E = in_sizes[1] / 2;
    const int G = out_size;
    const int* srcp = ei;
    const int* dstp = ei + E;

    char* p = (char*)d_ws;
    auto alloc = [&](size_t bytes) {
        char* r = p;
        p += (bytes + 255) & ~size_t(255);
        return r;
    };
    unsigned short* aggh = (unsigned short*)alloc((size_t)N * 64 * 2);
    unsigned short* vb   = (unsigned short*)alloc((size_t)N * 64 * 2);
    int*   col    = (int*)  alloc((size_t)N * DEGCAP * 4);
    int*   rank_  = (int*)  alloc((size_t)E * 4);
    unsigned short* x16h = (unsigned short*)alloc((size_t)N * 16 * 2);
    float* h16    = (float*)alloc((size_t)N * 16 * 4);
    int*   gstart = (int*)  alloc((size_t)(G + 1) * 4);
    float* ab     = (float*)alloc(5 * 128 * 4);
    half_t* wfrag = (half_t*)alloc((size_t)10 * 8192 * 2);
    // ---- zeroed region (single memset) ----
    char*  z0     = p;
    int*   cntn   = (int*)  alloc((size_t)N * 4);
    int*   cntg   = (int*)  alloc((size_t)G * 4);
    float* S      = (float*)alloc((size_t)5 * G * 64 * 4);
    float* bnpart = (float*)alloc((size_t)5 * 32 * 128 * 4);
    size_t zbytes = (size_t)(p - z0);

    hipMemsetAsync(z0, 0, zbytes, stream);

    int nb_e = (E + 255) / 256;
    int nb_n = (N + 255) / 256;
    k_histw<<<nb_e + 10, 256, 0, stream>>>(dstp, E, cntn, rank_,
                                           W1a, W1b, Wa, Wb, wfrag);
    k_fillprep<<<nb_n + nb_e, 256, 0, stream>>>(srcp, dstp, rank_, E, col,
                                                x, x16h, batch, cntg, N, nb_n);

    int nb_node = (N + 3) / 4;
    int nb_tile = (N + 63) / 64;
    int nbp = (G + 3) / 4;
    const size_t FR = 8192;   // halfs per packed matrix

    // Layer 1: 16-dim fp16 gather (+ scang extra block), then mlp<FIRST>
    k_gather16<<<nb_node + 1, 256, 0, stream>>>(x16h, h16, cntn, col, N,
                                                nb_node, cntg, G, gstart);
    k_mlp<true><<<nb_tile, 256, 0, stream>>>(h16, vb,
        wfrag + 0 * FR, b1a, wfrag + 1 * FR, b1b, bnpart,
        ab, cntn, N);

    // Layers 2-5: merged [pool(l) || gather(l+1)] then mlp (affine in mlp)
    for (int l = 0; l < 4; ++l) {
        k_pgather<<<nbp + 1 + nb_node, 256, 0, stream>>>(vb, gstart,
            S + (size_t)l * G * 64,
            bnpart + (size_t)l * 32 * 128,
            gamma + l * 64, beta + l * 64,
            ab + l * 128, ab + l * 128 + 64,
            aggh, cntn, col, N, G, nbp);
        k_mlp<false><<<nb_tile, 256, 0, stream>>>(aggh, vb,
            wfrag + (size_t)(2 + l) * FR, ba + l * 64,
            wfrag + (size_t)(6 + l) * FR, bb + l * 64,
            bnpart + (size_t)(l + 1) * 32 * 128,
            ab + l * 128, cntn, N);
    }

    // Last layer's pooling + BN finalize, then head.
    k_pool_bn<<<nbp + 1, 256, 0, stream>>>(vb, gstart,
        S + (size_t)4 * G * 64, bnpart + (size_t)4 * 32 * 128,
        gamma + 4 * 64, beta + 4 * 64,
        ab + 4 * 128, ab + 4 * 128 + 64, N, G, nbp);
    k_final<<<(G + 3) / 4, 256, 0, stream>>>(S, ab, cntg, fc1W, fc1b, fc2W, fc2b,
                                             (float*)d_out, G);
}